// Round 3
// baseline (484.198 us; speedup 1.0000x reference)
//
#include <hip/hip_runtime.h>
#include <hip/hip_bf16.h>

// Problem constants (from reference): B=16, M=8, S=100, P=40, A=3, D=128, H=8, HD=16
// Inputs are float32 (per reference dtypes); output is float32 (reference output dtype).
namespace {
constexpr int Bn = 16, Mn = 8, Sn = 100, Pn = 40, Dn = 128, Hn = 8;
constexpr int Nn = Bn * Mn * Sn;        // 12800 segments
constexpr int OUT0 = Sn * Bn * Mn * Dn; // 1638400 elements in output 0
}

// ---------------------------------------------------------------------------
// K0: precompute qk[h][c] = scale * sum_j q[h*16+j] * wk[c][h*16+j]
//     and qbk[h] = scale * sum_j q[h*16+j] * bk[h*16+j]
//     where q = map_seeds @ wq + bq   (constant across all segments).
// 1 block, 128 threads.
// ---------------------------------------------------------------------------
__global__ void k0_precompute(const float* __restrict__ ms, const float* __restrict__ wq,
                              const float* __restrict__ wk, const float* __restrict__ bq,
                              const float* __restrict__ bk,
                              float* __restrict__ qk, float* __restrict__ qbk) {
    __shared__ float q[128];
    const int t = threadIdx.x; // 0..127
    float s = bq[t];
    for (int c = 0; c < 128; ++c) s += ms[c] * wq[c * 128 + t];
    q[t] = s;
    __syncthreads();
    // thread t owns column c = t of qk for all 8 heads
    for (int h = 0; h < 8; ++h) {
        float a = 0.f;
#pragma unroll
        for (int j = 0; j < 16; ++j) a += q[h * 16 + j] * wk[t * 128 + h * 16 + j];
        qk[h * 128 + t] = a * 0.25f; // HD^-0.5 = 0.25 folded in
    }
    if (t < 8) {
        float a = 0.f;
#pragma unroll
        for (int j = 0; j < 16; ++j) a += q[t * 16 + j] * bk[t * 16 + j];
        qbk[t] = a * 0.25f;
    }
}

// block-wide sum over 256 threads (threads >=128 must pass 0)
__device__ __forceinline__ float block_sum_256(float v, float* red) {
#pragma unroll
    for (int off = 32; off > 0; off >>= 1) v += __shfl_down(v, off);
    __syncthreads(); // protect red from any previous use
    if ((threadIdx.x & 63) == 0) red[threadIdx.x >> 6] = v;
    __syncthreads();
    return red[0] + red[1] + red[2] + red[3];
}

// ---------------------------------------------------------------------------
// K1: one block (256 thr) per segment — fully fused encoder.
// ---------------------------------------------------------------------------
__global__ __launch_bounds__(256) void k1_segment(
    const float* __restrict__ roads,
    const float* __restrict__ lin_w, const float* __restrict__ lin_b,
    const float* __restrict__ wv, const float* __restrict__ bv,
    const float* __restrict__ out_w, const float* __restrict__ out_b,
    const float* __restrict__ ln1_g, const float* __restrict__ ln1_b,
    const float* __restrict__ w1, const float* __restrict__ b1,
    const float* __restrict__ w2, const float* __restrict__ b2,
    const float* __restrict__ ln2_g, const float* __restrict__ ln2_b,
    const float* __restrict__ qk_g, const float* __restrict__ qbk_g,
    float* __restrict__ out) {
    const int n = blockIdx.x;
    const int t = threadIdx.x;

    __shared__ float feats[40][129];   // +1 pad: breaks 128-stride bank aliasing
    __shared__ float qk_s[8][132];     // +4 pad
    __shared__ float qbk_s[8];
    __shared__ float attn_s[8][40];    // scores -> attn
    __shared__ float pooled[8][129];
    __shared__ float ctxs[128];
    __shared__ float embp[128];        // emb_pre -> emb (post-LN1)
    __shared__ float hidden[384];
    __shared__ float lastv[40];
    __shared__ float red[4];
    __shared__ float emptyf;

    // stage qk into LDS
    for (int i = t; i < 1024; i += 256) qk_s[i >> 7][i & 127] = qk_g[i];
    if (t < 8) qbk_s[t] = qbk_g[t];

    const int base = n * (Pn * 4);
    if (t < 40) lastv[t] = roads[base + t * 4 + 3];
    __syncthreads();

    if (t == 0) {
        float c = 0.f;
        for (int p = 0; p < 40; ++p) c += lastv[p];
        float e = (c == 0.f) ? 1.f : 0.f;
        emptyf = e;
        out[OUT0 + n] = e; // seg_mask (K2 fixes all_seg at s=0)
    }

    // feats[p][d] = roads[p,0:3] @ lin_w + lin_b
    for (int i = t; i < 40 * 128; i += 256) {
        const int p = i >> 7, d = i & 127;
        const float a0 = roads[base + p * 4 + 0];
        const float a1 = roads[base + p * 4 + 1];
        const float a2 = roads[base + p * 4 + 2];
        feats[p][d] = a0 * lin_w[d] + a1 * lin_w[128 + d] +
                      a2 * lin_w[256 + d] + lin_b[d];
    }
    __syncthreads();

    // scores[h][p] = qbk[h] + feats[p,:] . qk[h,:]  (scale pre-folded), then mask
    const float empty = emptyf;
    for (int i = t; i < 8 * 40; i += 256) {
        const int h = i & 7, p = i >> 3;
        float s = qbk_s[h];
#pragma unroll 8
        for (int c = 0; c < 128; ++c) s += feats[p][c] * qk_s[h][c];
        const bool masked = (lastv[p] == 0.f) && !((empty != 0.f) && (p == 0));
        attn_s[h][p] = masked ? -1e9f : s;
    }
    __syncthreads();

    // softmax per head (serial over 40, 8 threads)
    if (t < 8) {
        float mx = -1e30f;
        for (int p = 0; p < 40; ++p) mx = fmaxf(mx, attn_s[t][p]);
        float sum = 0.f;
        for (int p = 0; p < 40; ++p) {
            const float e = __expf(attn_s[t][p] - mx);
            attn_s[t][p] = e;
            sum += e;
        }
        const float inv = 1.f / sum;
        for (int p = 0; p < 40; ++p) attn_s[t][p] *= inv;
    }
    __syncthreads();

    // pooled[h][c] = sum_p attn[h][p] * feats[p][c]
    for (int i = t; i < 8 * 128; i += 256) {
        const int h = i >> 7, c = i & 127;
        float s = 0.f;
#pragma unroll 8
        for (int p = 0; p < 40; ++p) s += attn_s[h][p] * feats[p][c];
        pooled[h][c] = s;
    }
    __syncthreads();

    // ctx[e] = bv[e] + sum_c pooled[h(e)][c] * wv[c][e]
    if (t < 128) {
        const int h = t >> 4;
        float s = bv[t];
#pragma unroll 8
        for (int c = 0; c < 128; ++c) s += pooled[h][c] * wv[c * 128 + t];
        ctxs[t] = s;
    }
    __syncthreads();

    // emb_pre[d] = out_b[d] + sum_e ctx[e] * out_w[e][d]
    if (t < 128) {
        float s = out_b[t];
#pragma unroll 8
        for (int e = 0; e < 128; ++e) s += ctxs[e] * out_w[e * 128 + t];
        embp[t] = s;
    }

    // LN1
    {
        const float x = (t < 128) ? embp[t] : 0.f; // own value, no barrier needed
        const float mu = block_sum_256(x, red) * (1.f / 128.f);
        const float dx = (t < 128) ? (x - mu) : 0.f;
        const float var = block_sum_256(dx * dx, red) * (1.f / 128.f);
        const float rstd = rsqrtf(var + 1e-5f);
        if (t < 128) embp[t] = (x - mu) * rstd * ln1_g[t] + ln1_b[t];
    }
    __syncthreads();

    // hidden[j] = relu(emb . w1[:,j] + b1[j])
    for (int i = t; i < 384; i += 256) {
        float s = b1[i];
#pragma unroll 8
        for (int d = 0; d < 128; ++d) s += embp[d] * w1[d * 384 + i];
        hidden[i] = fmaxf(s, 0.f);
    }
    __syncthreads();

    // y[d] = emb[d] + hidden . w2[:,d] + b2[d], then LN2, transposed store
    float y = 0.f;
    if (t < 128) {
        float s = b2[t];
#pragma unroll 8
        for (int j = 0; j < 384; ++j) s += hidden[j] * w2[j * 128 + t];
        y = embp[t] + s;
    }
    {
        const float x = (t < 128) ? y : 0.f;
        const float mu = block_sum_256(x, red) * (1.f / 128.f);
        const float dx = (t < 128) ? (x - mu) : 0.f;
        const float var = block_sum_256(dx * dx, red) * (1.f / 128.f);
        const float rstd = rsqrtf(var + 1e-5f);
        if (t < 128) {
            const float o = (x - mu) * rstd * ln2_g[t] + ln2_b[t];
            const int s_idx = n % 100, bm = n / 100;   // n = bm*100 + s
            out[(s_idx * 128 + bm) * 128 + t] = o; // (S,B,M,D)
        }
    }
}

// ---------------------------------------------------------------------------
// K2: all_seg fix — if all S segments of a (b,m) are empty, unmask s=0.
// 1 block, 128 threads (one per (b,m)).
// ---------------------------------------------------------------------------
__global__ void k2_fix_segmask(float* __restrict__ out) {
    const int bm = threadIdx.x; // 0..127
    const int base = OUT0 + bm * Sn;
    bool all = true;
    for (int s = 0; s < Sn; ++s) all = all && (out[base + s] != 0.f);
    if (all) out[base] = 0.f;
}

extern "C" void kernel_launch(void* const* d_in, const int* in_sizes, int n_in,
                              void* d_out, int out_size, void* d_ws, size_t ws_size,
                              hipStream_t stream) {
    const float* roads   = (const float*)d_in[0];
    // d_in[1] = agents_emb (unused by reference)
    const float* ms      = (const float*)d_in[2];
    const float* lin_w   = (const float*)d_in[3];
    const float* lin_b   = (const float*)d_in[4];
    const float* wq      = (const float*)d_in[5];
    const float* wk      = (const float*)d_in[6];
    const float* wv      = (const float*)d_in[7];
    const float* bq      = (const float*)d_in[8];
    const float* bk      = (const float*)d_in[9];
    const float* bv      = (const float*)d_in[10];
    const float* out_w   = (const float*)d_in[11];
    const float* out_b   = (const float*)d_in[12];
    const float* ln1_g   = (const float*)d_in[13];
    const float* ln1_b   = (const float*)d_in[14];
    const float* w1      = (const float*)d_in[15];
    const float* b1      = (const float*)d_in[16];
    const float* w2      = (const float*)d_in[17];
    const float* b2      = (const float*)d_in[18];
    const float* ln2_g   = (const float*)d_in[19];
    const float* ln2_b   = (const float*)d_in[20];

    float* out = (float*)d_out;
    float* qk  = (float*)d_ws;      // 1024 floats
    float* qbk = qk + 1024;         // 8 floats

    k0_precompute<<<1, 128, 0, stream>>>(ms, wq, wk, bq, bk, qk, qbk);
    k1_segment<<<Nn, 256, 0, stream>>>(roads, lin_w, lin_b, wv, bv, out_w, out_b,
                                       ln1_g, ln1_b, w1, b1, w2, b2, ln2_g, ln2_b,
                                       qk, qbk, out);
    k2_fix_segmask<<<1, 128, 0, stream>>>(out);
}

// Round 4
// 191.394 us; speedup vs baseline: 2.5298x; 2.5298x over previous
//
#include <hip/hip_runtime.h>

// B=16, M=8, S=100, P=40, A=3, D=128, H=8, HD=16. Inputs fp32, output fp32.
// Algebra: feats = [a0,a1,a2,1] @ W4  (rank-4!)  =>
//   scores = pts4 @ W4qk (4x8, qbk folded into row 3 since pts4[3]=1)
//   apool[seg,h,j] = sum_p attn[h,p]*pts4[p,j]   (apool[.,3] = 1 -> bv folds)
//   emb_pre[d] = out_b[d] + sum_{h,j} apool[h,j] * T[h*4+j][d]
//   where T[hj][d] = sum_{e in head h} (W4 @ wv + bv_fold)[j,e] * out_w[e,d]
namespace {
constexpr int Sn = 100, Pn = 40;
constexpr int Nn = 12800;               // B*M*S
constexpr int OUT0 = 1638400;           // S*B*M*D
constexpr int G1 = 16;                  // segments per k1 block
constexpr int RB = 32;                  // rows per ffn block
}

// ---------------------------------------------------------------------------
// K0: 40 blocks x 128 thr. Blocks 0..7 (h): W4qk column h. Blocks 8..39 (hj): T row.
// ---------------------------------------------------------------------------
__global__ __launch_bounds__(128) void k0_precompute(
    const float* __restrict__ ms, const float* __restrict__ wq,
    const float* __restrict__ wk, const float* __restrict__ bq,
    const float* __restrict__ bk, const float* __restrict__ lin_w,
    const float* __restrict__ lin_b, const float* __restrict__ wv,
    const float* __restrict__ bv, const float* __restrict__ out_w,
    float* __restrict__ W4qk, float* __restrict__ T) {
  const int t = threadIdx.x;
  if (blockIdx.x < 8) {
    const int h = blockIdx.x;
    __shared__ float q[128];
    __shared__ float qkh[128];
    __shared__ float qbkh;
    __shared__ float part[128];
    float s = bq[t];
    for (int c = 0; c < 128; ++c) s += ms[c] * wq[c * 128 + t];
    q[t] = s;
    __syncthreads();
    float a = 0.f;
#pragma unroll
    for (int j = 0; j < 16; ++j) a += q[h * 16 + j] * wk[t * 128 + h * 16 + j];
    qkh[t] = a * 0.25f;                       // scale folded
    if (t == 0) {
      float b = 0.f;
#pragma unroll
      for (int j = 0; j < 16; ++j) b += q[h * 16 + j] * bk[h * 16 + j];
      qbkh = b * 0.25f;
    }
    __syncthreads();
    const int j = t >> 5, cp = t & 31;        // j 0..3, 32 partials each
    float p = 0.f;
    for (int c = cp * 4; c < cp * 4 + 4; ++c) {
      const float w4 = (j < 3) ? lin_w[j * 128 + c] : lin_b[c];
      p += w4 * qkh[c];
    }
    part[t] = p;
    __syncthreads();
    if (t < 4) {
      float sum = 0.f;
      for (int i = 0; i < 32; ++i) sum += part[t * 32 + i];
      if (t == 3) sum += qbkh;                // qbk folds into j=3 (pts4[3]==1)
      W4qk[t * 8 + h] = sum;
    }
  } else {
    const int hj = blockIdx.x - 8;            // 0..31
    const int h = hj >> 2, j = hj & 3;
    __shared__ float part[128];
    __shared__ float w4wv[16];
    const int e = t >> 3, cp = t & 7;
    float p = 0.f;
    for (int c = cp * 16; c < cp * 16 + 16; ++c) {
      const float w4 = (j < 3) ? lin_w[j * 128 + c] : lin_b[c];
      p += w4 * wv[c * 128 + (h * 16 + e)];
    }
    part[t] = p;
    __syncthreads();
    if (t < 16) {
      float sum = 0.f;
      for (int i = 0; i < 8; ++i) sum += part[t * 8 + i];
      if (j == 3) sum += bv[h * 16 + t];      // bv folds (pts4[3]==1)
      w4wv[t] = sum;
    }
    __syncthreads();
    float acc = 0.f;
#pragma unroll
    for (int e2 = 0; e2 < 16; ++e2) acc += w4wv[e2] * out_w[(h * 16 + e2) * 128 + t];
    T[hj * 128 + t] = acc;
  }
}

// ---------------------------------------------------------------------------
// K1: 800 blocks x 256 thr, 16 segments each: scores->softmax->apool->emb->LN1.
// Writes LN1'd emb to its FINAL out location (k3 reads+overwrites in place).
// ---------------------------------------------------------------------------
__global__ __launch_bounds__(256) void k1_attn(
    const float* __restrict__ roads,
    const float* __restrict__ W4qk, const float* __restrict__ T,
    const float* __restrict__ out_b,
    const float* __restrict__ ln1_g, const float* __restrict__ ln1_b,
    float* __restrict__ out) {
  const int t = threadIdx.x;
  const int n0 = blockIdx.x * G1;
  __shared__ float pts[G1 * 40][5];     // [pp][a0,a1,a2,last], +1 pad
  __shared__ float attn[G1 * 8][41];    // [seg*8+h][p], pad 41 (bank spread)
  __shared__ float apool[G1][33];
  __shared__ float embp[G1][132];
  __shared__ float w4qk_l[32];
  __shared__ float emptyv[G1];

  for (int pp = t; pp < G1 * 40; pp += 256) {
    const float4 r4 = ((const float4*)roads)[n0 * 40 + pp];
    pts[pp][0] = r4.x; pts[pp][1] = r4.y; pts[pp][2] = r4.z; pts[pp][3] = r4.w;
  }
  if (t < 32) w4qk_l[t] = W4qk[t];
  __syncthreads();

  if (t < G1) {
    float s = 0.f;
    for (int p = 0; p < 40; ++p) s += pts[t * 40 + p][3];
    const float e = (s == 0.f) ? 1.f : 0.f;
    emptyv[t] = e;
    out[OUT0 + n0 + t] = e;               // seg_mask (k2 fixes all_seg)
  }
  __syncthreads();

  // scores (scale+qbk pre-folded), mask
  for (int i = t; i < G1 * 8 * 40; i += 256) {
    const int seg = i / 320, rem = i - seg * 320;
    const int h = rem / 40, p = rem - h * 40;
    const int pp = seg * 40 + p;
    float s = w4qk_l[24 + h];
    s += pts[pp][0] * w4qk_l[h] + pts[pp][1] * w4qk_l[8 + h] + pts[pp][2] * w4qk_l[16 + h];
    const bool masked = (pts[pp][3] == 0.f) && !((emptyv[seg] != 0.f) && (p == 0));
    attn[seg * 8 + h][p] = masked ? -1e9f : s;
  }
  __syncthreads();

  if (t < G1 * 8) {                       // softmax, one (seg,h) per thread
    float mx = -1e30f;
    for (int p = 0; p < 40; ++p) mx = fmaxf(mx, attn[t][p]);
    float sum = 0.f;
    for (int p = 0; p < 40; ++p) { const float e = __expf(attn[t][p] - mx); attn[t][p] = e; sum += e; }
    const float inv = 1.f / sum;
    for (int p = 0; p < 40; ++p) attn[t][p] *= inv;
  }
  __syncthreads();

  for (int i = t; i < G1 * 32; i += 256) { // apool
    const int seg = i >> 5, hj = i & 31, h = hj >> 2, j = hj & 3;
    float s = 0.f;
    for (int p = 0; p < 40; ++p) s += attn[seg * 8 + h][p] * pts[seg * 40 + p][j];
    apool[seg][hj] = s;
  }
  __syncthreads();

  {                                       // emb_pre = apool @ T + out_b
    const int d = t & 127, half = t >> 7;
    const float ob = out_b[d];
    float acc[8];
#pragma unroll
    for (int r = 0; r < 8; ++r) acc[r] = ob;
    for (int hj = 0; hj < 32; ++hj) {
      const float tv = T[hj * 128 + d];
#pragma unroll
      for (int r = 0; r < 8; ++r) acc[r] += apool[half + 2 * r][hj] * tv;
    }
#pragma unroll
    for (int r = 0; r < 8; ++r) embp[half + 2 * r][d] = acc[r];
  }
  __syncthreads();

  {                                       // LN1 + store to final location
    const int seg = t >> 4, l = t & 15;
    float x[8];
#pragma unroll
    for (int i = 0; i < 8; ++i) x[i] = embp[seg][l * 8 + i];
    float s = 0.f;
#pragma unroll
    for (int i = 0; i < 8; ++i) s += x[i];
#pragma unroll
    for (int m = 1; m < 16; m <<= 1) s += __shfl_xor(s, m, 16);
    const float mu = s * (1.f / 128.f);
    float v = 0.f;
#pragma unroll
    for (int i = 0; i < 8; ++i) { const float dx = x[i] - mu; v += dx * dx; }
#pragma unroll
    for (int m = 1; m < 16; m <<= 1) v += __shfl_xor(v, m, 16);
    const float rstd = rsqrtf(v * (1.f / 128.f) + 1e-5f);
    const int n = n0 + seg, s_i = n % 100, bm = n / 100;
    float* orow = out + (size_t)s_i * 16384 + bm * 128 + l * 8;
#pragma unroll
    for (int i = 0; i < 8; ++i) orow[i] = (x[i] - mu) * rstd * ln1_g[l * 8 + i] + ln1_b[l * 8 + i];
  }
}

// ---------------------------------------------------------------------------
// K3: FFN + residual + LN2, in-place on out. 400 blocks x 256 thr, 32 rows each.
// Register-blocked 8x2; activations broadcast from LDS (transposed, padded).
// ---------------------------------------------------------------------------
__global__ __launch_bounds__(256) void k3_ffn(
    const float* __restrict__ w1, const float* __restrict__ b1,
    const float* __restrict__ w2, const float* __restrict__ b2,
    const float* __restrict__ ln2_g, const float* __restrict__ ln2_b,
    float* __restrict__ out) {
  const int t = threadIdx.x;
  const int n0 = blockIdx.x * RB;
  __shared__ float embT[128][36];   // [k][r], pad 36 keeps float4 alignment
  __shared__ float hidT[384][36];

  for (int it = 0; it < 4; ++it) {  // stage emb tile
    const int i4 = t + 256 * it;    // 0..1023
    const int r = i4 >> 5, d4 = (i4 & 31) * 4;
    const int n = n0 + r, s_i = n % 100, bm = n / 100;
    const float4 e4 = *(const float4*)(out + (size_t)s_i * 16384 + bm * 128 + d4);
    embT[d4 + 0][r] = e4.x; embT[d4 + 1][r] = e4.y;
    embT[d4 + 2][r] = e4.z; embT[d4 + 3][r] = e4.w;
  }
  __syncthreads();

  const int rg = t >> 6, cp = t & 63, r0 = rg * 8;  // wave == rg

  for (int ci = 0; ci < 3; ++ci) {  // GEMM1: hidden = relu(emb@w1+b1)
    const int c0 = 2 * (ci * 64 + cp);
    float a0[8], a1[8];
#pragma unroll
    for (int r = 0; r < 8; ++r) { a0[r] = 0.f; a1[r] = 0.f; }
    for (int k = 0; k < 128; ++k) {
      const float2 w = *(const float2*)(w1 + k * 384 + c0);
      const float4 ea = *(const float4*)&embT[k][r0];
      const float4 eb = *(const float4*)&embT[k][r0 + 4];
      a0[0] += ea.x * w.x; a1[0] += ea.x * w.y;
      a0[1] += ea.y * w.x; a1[1] += ea.y * w.y;
      a0[2] += ea.z * w.x; a1[2] += ea.z * w.y;
      a0[3] += ea.w * w.x; a1[3] += ea.w * w.y;
      a0[4] += eb.x * w.x; a1[4] += eb.x * w.y;
      a0[5] += eb.y * w.x; a1[5] += eb.y * w.y;
      a0[6] += eb.z * w.x; a1[6] += eb.z * w.y;
      a0[7] += eb.w * w.x; a1[7] += eb.w * w.y;
    }
    const float2 bb = *(const float2*)(b1 + c0);
    float4 ha, hb;
    ha.x = fmaxf(a0[0] + bb.x, 0.f); ha.y = fmaxf(a0[1] + bb.x, 0.f);
    ha.z = fmaxf(a0[2] + bb.x, 0.f); ha.w = fmaxf(a0[3] + bb.x, 0.f);
    hb.x = fmaxf(a0[4] + bb.x, 0.f); hb.y = fmaxf(a0[5] + bb.x, 0.f);
    hb.z = fmaxf(a0[6] + bb.x, 0.f); hb.w = fmaxf(a0[7] + bb.x, 0.f);
    *(float4*)&hidT[c0][r0] = ha; *(float4*)&hidT[c0][r0 + 4] = hb;
    ha.x = fmaxf(a1[0] + bb.y, 0.f); ha.y = fmaxf(a1[1] + bb.y, 0.f);
    ha.z = fmaxf(a1[2] + bb.y, 0.f); ha.w = fmaxf(a1[3] + bb.y, 0.f);
    hb.x = fmaxf(a1[4] + bb.y, 0.f); hb.y = fmaxf(a1[5] + bb.y, 0.f);
    hb.z = fmaxf(a1[6] + bb.y, 0.f); hb.w = fmaxf(a1[7] + bb.y, 0.f);
    *(float4*)&hidT[c0 + 1][r0] = ha; *(float4*)&hidT[c0 + 1][r0 + 4] = hb;
  }
  __syncthreads();

  {  // GEMM2 + residual + LN2 + transposed store
    const int c0 = 2 * cp;
    float a0[8], a1[8];
#pragma unroll
    for (int r = 0; r < 8; ++r) { a0[r] = 0.f; a1[r] = 0.f; }
    for (int k = 0; k < 384; ++k) {
      const float2 w = *(const float2*)(w2 + k * 128 + c0);
      const float4 ea = *(const float4*)&hidT[k][r0];
      const float4 eb = *(const float4*)&hidT[k][r0 + 4];
      a0[0] += ea.x * w.x; a1[0] += ea.x * w.y;
      a0[1] += ea.y * w.x; a1[1] += ea.y * w.y;
      a0[2] += ea.z * w.x; a1[2] += ea.z * w.y;
      a0[3] += ea.w * w.x; a1[3] += ea.w * w.y;
      a0[4] += eb.x * w.x; a1[4] += eb.x * w.y;
      a0[5] += eb.y * w.x; a1[5] += eb.y * w.y;
      a0[6] += eb.z * w.x; a1[6] += eb.z * w.y;
      a0[7] += eb.w * w.x; a1[7] += eb.w * w.y;
    }
    const float2 bb = *(const float2*)(b2 + c0);
    const float2 g2 = *(const float2*)(ln2_g + c0);
    const float2 bl = *(const float2*)(ln2_b + c0);
#pragma unroll
    for (int jr = 0; jr < 8; ++jr) {
      float y0 = a0[jr] + bb.x + embT[c0][r0 + jr];
      float y1 = a1[jr] + bb.y + embT[c0 + 1][r0 + jr];
      float s = y0 + y1;
#pragma unroll
      for (int m = 1; m < 64; m <<= 1) s += __shfl_xor(s, m);
      const float mu = s * (1.f / 128.f);
      const float d0 = y0 - mu, d1 = y1 - mu;
      float v = d0 * d0 + d1 * d1;
#pragma unroll
      for (int m = 1; m < 64; m <<= 1) v += __shfl_xor(v, m);
      const float rstd = rsqrtf(v * (1.f / 128.f) + 1e-5f);
      const int n = n0 + r0 + jr, s_i = n % 100, bm = n / 100;
      float2 o;
      o.x = d0 * rstd * g2.x + bl.x;
      o.y = d1 * rstd * g2.y + bl.y;
      *(float2*)(out + (size_t)s_i * 16384 + bm * 128 + c0) = o;
    }
  }
}

// ---------------------------------------------------------------------------
// K2: all_seg fix — if all S segments of a (b,m) are empty, unmask s=0.
// ---------------------------------------------------------------------------
__global__ void k2_fix_segmask(float* __restrict__ out) {
  const int bm = threadIdx.x;  // 0..127
  const int base = OUT0 + bm * Sn;
  bool all = true;
  for (int s = 0; s < Sn; ++s) all = all && (out[base + s] != 0.f);
  if (all) out[base] = 0.f;
}

extern "C" void kernel_launch(void* const* d_in, const int* in_sizes, int n_in,
                              void* d_out, int out_size, void* d_ws, size_t ws_size,
                              hipStream_t stream) {
  const float* roads = (const float*)d_in[0];
  const float* ms    = (const float*)d_in[2];
  const float* lin_w = (const float*)d_in[3];
  const float* lin_b = (const float*)d_in[4];
  const float* wq    = (const float*)d_in[5];
  const float* wk    = (const float*)d_in[6];
  const float* wv    = (const float*)d_in[7];
  const float* bq    = (const float*)d_in[8];
  const float* bk    = (const float*)d_in[9];
  const float* bv    = (const float*)d_in[10];
  const float* out_w = (const float*)d_in[11];
  const float* out_b = (const float*)d_in[12];
  const float* ln1_g = (const float*)d_in[13];
  const float* ln1_b = (const float*)d_in[14];
  const float* w1    = (const float*)d_in[15];
  const float* b1    = (const float*)d_in[16];
  const float* w2    = (const float*)d_in[17];
  const float* b2    = (const float*)d_in[18];
  const float* ln2_g = (const float*)d_in[19];
  const float* ln2_b = (const float*)d_in[20];

  float* out  = (float*)d_out;
  float* W4qk = (float*)d_ws;      // 32 floats
  float* T    = W4qk + 32;         // 4096 floats

  k0_precompute<<<40, 128, 0, stream>>>(ms, wq, wk, bq, bk, lin_w, lin_b, wv, bv, out_w, W4qk, T);
  k1_attn<<<Nn / G1, 256, 0, stream>>>(roads, W4qk, T, out_b, ln1_g, ln1_b, out);
  k3_ffn<<<Nn / RB, 256, 0, stream>>>(w1, b1, w2, b2, ln2_g, ln2_b, out);
  k2_fix_segmask<<<1, 128, 0, stream>>>(out);
}